// Round 6
// baseline (209.176 us; speedup 1.0000x reference)
//
#include <hip/hip_runtime.h>

typedef _Float16 half8 __attribute__((ext_vector_type(8)));
typedef _Float16 half2v __attribute__((ext_vector_type(2)));
typedef __fp16   fp16x2 __attribute__((ext_vector_type(2)));
typedef float    f32x4 __attribute__((ext_vector_type(4)));

// Fragment layout (validated R1/R2/R4 end-to-end):
//   value = Wsrc[k][m] at lane l, elem j:  m = mt*16 + (l&15),
//   k = ks*32 + 16*(j>>2) + ((l>>4)<<2) + (j&3)
// ws (halfs): L1..L3 W^T frags at (i-1)*16384 + (mt*4+ks)*512 + lane*8
//             W4^T at 49152 + ks*512 + lane*8
//             W0ext (k=0 row -> W0, k=1 row -> b0) at 53248 + mt*512 + lane*8

__global__ __launch_bounds__(256) void prep_kernel(
    const float* __restrict__ W1, const float* __restrict__ W2,
    const float* __restrict__ W3, const float* __restrict__ W4,
    const float* __restrict__ W0, const float* __restrict__ b0,
    _Float16* __restrict__ out)
{
    int t = blockIdx.x * blockDim.x + threadIdx.x;
    if (t >= 6912) return;
    int lane = t & 63;
    int frag = t >> 6;                 // 0..107
    int col  = lane & 15;
    int kq   = (lane >> 4) << 2;

    if (frag < 96) {
        int l = frag >> 5, f = frag & 31;
        const float* W = (l == 0) ? W1 : (l == 1) ? W2 : W3;
        int mt = f >> 2, ks = f & 3;
        _Float16* dst = out + l * 16384 + f * 512 + lane * 8;
        int m = mt * 16 + col;
        int kbase = ks * 32 + kq;
#pragma unroll
        for (int j = 0; j < 8; ++j) {
            int k = kbase + 16 * (j >> 2) + (j & 3);
            dst[j] = (_Float16)W[k * 128 + m];
        }
    } else if (frag < 100) {
        int ks = frag - 96;
        _Float16* dst = out + 49152 + ks * 512 + lane * 8;
        int m = col;
        int kbase = ks * 32 + kq;
#pragma unroll
        for (int j = 0; j < 8; ++j) {
            int k = kbase + 16 * (j >> 2) + (j & 3);
            float v = (m < 14) ? W4[k * 14 + m] : 0.0f;
            dst[j] = (_Float16)v;
        }
    } else {
        int mt = frag - 100;
        _Float16* dst = out + 53248 + mt * 512 + lane * 8;
        int m = mt * 16 + col;
#pragma unroll
        for (int j = 0; j < 8; ++j) {
            int k = 16 * (j >> 2) + kq + (j & 3);
            float v = (k == 0) ? W0[m] : (k == 1) ? b0[m] : 0.0f;
            dst[j] = (_Float16)v;
        }
    }
}

static __device__ __forceinline__ half2v relu_cvt2(float a, float b) {
    fp16x2 h = __builtin_amdgcn_cvt_pkrtz(a, b);
    fp16x2 zz = {(__fp16)0.0f, (__fp16)0.0f};
    h = __builtin_elementwise_max(h, zz);
    return __builtin_bit_cast(half2v, h);
}

__global__ __launch_bounds__(256, 4) void nflow_kernel(
    const float* __restrict__ x, const float* __restrict__ z,
    const float* __restrict__ b1, const float* __restrict__ b2,
    const float* __restrict__ b3, const float* __restrict__ b4v,
    const _Float16* __restrict__ Af, float* __restrict__ y, int N)
{
    __shared__ float phis[64][20];   // 5120 B; stride 20 f32 = 80 B keeps b128 aligned

    const int tid  = threadIdx.x;
    const int lane = tid & 63;
    const int wid  = tid >> 6;
    const int col  = lane & 15;
    const int quad = lane >> 4;
    const int s0   = blockIdx.x * 64 + wid * 16 + col;   // this wave's sample

    half8 b[4];   // B-fragments of h: n = col (sample), k per fragment formula

    // ---- layer 0 as MFMA: h0 = relu([x,1]·[W0;b0])
    {
        float xv = (s0 < N) ? x[s0] : 0.0f;
        half8 bx = {};
        if (quad == 0) { bx[0] = (_Float16)xv; bx[1] = (_Float16)1.0f; }
        f32x4 acc[8];
        __builtin_amdgcn_s_setprio(1);
#pragma unroll
        for (int mt = 0; mt < 8; ++mt) {
            half8 a = *(const half8*)(Af + 53248 + mt * 512 + lane * 8);
            acc[mt] = __builtin_amdgcn_mfma_f32_16x16x32_f16(a, bx, (f32x4){0.f,0.f,0.f,0.f}, 0, 0, 0);
        }
        __builtin_amdgcn_s_setprio(0);
#pragma unroll
        for (int ks = 0; ks < 4; ++ks)
#pragma unroll
            for (int p = 0; p < 4; ++p) {
                int mt = 2 * ks + (p >> 1), r = 2 * (p & 1);
                half2v h = relu_cvt2(acc[mt][r], acc[mt][r + 1]);
                b[ks][2 * p]     = h[0];
                b[ks][2 * p + 1] = h[1];
            }
    }

    // ---- hidden layers 1..3 (bias folded into acc init)
#pragma unroll
    for (int l = 0; l < 3; ++l) {
        const _Float16* Al = Af + l * 16384;
        const float* bias = (l == 0) ? b1 : (l == 1) ? b2 : b3;

        f32x4 acc[8];
#pragma unroll
        for (int mt = 0; mt < 8; ++mt)
            acc[mt] = *(const f32x4*)(bias + mt * 16 + quad * 4);

        __builtin_amdgcn_s_setprio(1);
#pragma unroll
        for (int ks = 0; ks < 4; ++ks) {
#pragma unroll
            for (int mt = 0; mt < 8; ++mt) {
                half8 a = *(const half8*)(Al + (mt * 4 + ks) * 512 + lane * 8);
                acc[mt] = __builtin_amdgcn_mfma_f32_16x16x32_f16(a, b[ks], acc[mt], 0, 0, 0);
            }
        }
        __builtin_amdgcn_s_setprio(0);

#pragma unroll
        for (int ks = 0; ks < 4; ++ks)
#pragma unroll
            for (int p = 0; p < 4; ++p) {
                int mt = 2 * ks + (p >> 1), r = 2 * (p & 1);
                half2v h = relu_cvt2(acc[mt][r], acc[mt][r + 1]);
                b[ks][2 * p]     = h[0];
                b[ks][2 * p + 1] = h[1];
            }
    }

    // ---- layer 4: phi = W4^T·h + b4 (bias in acc init)
    {
        f32x4 acc4;
#pragma unroll
        for (int r = 0; r < 4; ++r) {
            int comp = quad * 4 + r;
            acc4[r] = (comp < 14) ? b4v[comp] : 0.0f;
        }
        __builtin_amdgcn_s_setprio(1);
#pragma unroll
        for (int ks = 0; ks < 4; ++ks) {
            half8 a = *(const half8*)(Af + 49152 + ks * 512 + lane * 8);
            acc4 = __builtin_amdgcn_mfma_f32_16x16x32_f16(a, b[ks], acc4, 0, 0, 0);
        }
        __builtin_amdgcn_s_setprio(0);
        *(f32x4*)&phis[wid * 16 + col][quad * 4] = acc4;
    }

    __syncthreads();

    // ---- RQS inverse: wave 0 handles the block's 64 samples, all lanes active
    if (tid < 64) {
        int gs = blockIdx.x * 64 + tid;
        if (gs < N) {
            float ph[16];
            *(f32x4*)&ph[0]  = *(const f32x4*)&phis[tid][0];
            *(f32x4*)&ph[4]  = *(const f32x4*)&phis[tid][4];
            *(f32x4*)&ph[8]  = *(const f32x4*)&phis[tid][8];
            *(f32x4*)&ph[12] = *(const f32x4*)&phis[tid][12];

            float mw = ph[0], mh = ph[5];
#pragma unroll
            for (int i = 1; i < 5; ++i) { mw = fmaxf(mw, ph[i]); mh = fmaxf(mh, ph[5 + i]); }
            float ew[5], eh[5];
            float sw = 0.f, sh = 0.f;
#pragma unroll
            for (int i = 0; i < 5; ++i) {
                ew[i] = __expf(ph[i] - mw);      sw += ew[i];
                eh[i] = __expf(ph[5 + i] - mh);  sh += eh[i];
            }
            float iw = 10.0f / sw, ih = 10.0f / sh;
            float xk[6], yk[6], dk[6];
            xk[0] = -5.0f; yk[0] = -5.0f;
#pragma unroll
            for (int i = 0; i < 5; ++i) {
                xk[i + 1] = xk[i] + ew[i] * iw;
                yk[i + 1] = yk[i] + eh[i] * ih;
            }
            dk[0] = 1.0f; dk[5] = 1.0f;
#pragma unroll
            for (int i = 0; i < 4; ++i) {
                float v = ph[10 + i];
                dk[i + 1] = 0.0001f + fmaxf(v, 0.0f) + __logf(1.0f + __expf(-fabsf(v)));
            }
            float zv = z[gs];
            float zc = fminf(fmaxf(zv, -5.0f), 5.0f);
            int k = 0;
#pragma unroll
            for (int i = 1; i <= 4; ++i) k += (zc >= yk[i]) ? 1 : 0;
            float x0 = xk[0], x1 = xk[1], y0 = yk[0], y1 = yk[1], d0 = dk[0], d1 = dk[1];
#pragma unroll
            for (int i = 1; i < 5; ++i)
                if (k == i) { x0 = xk[i]; x1 = xk[i + 1]; y0 = yk[i]; y1 = yk[i + 1]; d0 = dk[i]; d1 = dk[i + 1]; }
            float dx = x1 - x0, dy = y1 - y0;
            float s  = dy / dx;
            float tt = zc - y0;
            float mm = d0 + d1 - 2.0f * s;
            float aa = dy * (s - d0) + tt * mm;
            float bb2 = dy * d0 - tt * mm;
            float cc = -s * tt;
            float disc = fmaxf(bb2 * bb2 - 4.0f * aa * cc, 0.0f);
            float xi   = (2.0f * cc) / (-bb2 - sqrtf(disc));
            float xin  = x0 + xi * dx;
            y[gs] = (fabsf(zv) >= 5.0f) ? zv : xin;
        }
    }
}

extern "C" void kernel_launch(void* const* d_in, const int* in_sizes, int n_in,
                              void* d_out, int out_size, void* d_ws, size_t ws_size,
                              hipStream_t stream) {
    const float* x  = (const float*)d_in[0];
    const float* z  = (const float*)d_in[1];
    const float* W0 = (const float*)d_in[2];
    const float* b0 = (const float*)d_in[3];
    const float* W1 = (const float*)d_in[4];
    const float* b1 = (const float*)d_in[5];
    const float* W2 = (const float*)d_in[6];
    const float* b2 = (const float*)d_in[7];
    const float* W3 = (const float*)d_in[8];
    const float* b3 = (const float*)d_in[9];
    const float* W4 = (const float*)d_in[10];
    const float* b4 = (const float*)d_in[11];
    float* y = (float*)d_out;
    int N = in_sizes[0];

    _Float16* wsH = (_Float16*)d_ws;
    prep_kernel<<<27, 256, 0, stream>>>(W1, W2, W3, W4, W0, b0, wsH);
    int nblk = (N + 63) / 64;
    nflow_kernel<<<nblk, 256, 0, stream>>>(x, z, b1, b2, b3, b4, wsH, y, N);
}

// Round 7
// 124.777 us; speedup vs baseline: 1.6764x; 1.6764x over previous
//
#include <hip/hip_runtime.h>

typedef _Float16 half8 __attribute__((ext_vector_type(8)));
typedef _Float16 half2v __attribute__((ext_vector_type(2)));
typedef __fp16   fp16x2 __attribute__((ext_vector_type(2)));
typedef float    f32x4 __attribute__((ext_vector_type(4)));

// Fragment layout (validated R1/R2/R4/R6 end-to-end):
//   value = Wsrc[k][m] at lane l, elem j:  m = mt*16 + (l&15),
//   k = ks*32 + 16*(j>>2) + ((l>>4)<<2) + (j&3)
// ws (halfs): L1..L3 W^T frags at (i-1)*16384 + (mt*4+ks)*512 + lane*8
//             W4^T at 49152 + ks*512 + lane*8
//             W0ext (k=0 row -> W0, k=1 row -> b0) at 53248 + mt*512 + lane*8

__global__ __launch_bounds__(256) void prep_kernel(
    const float* __restrict__ W1, const float* __restrict__ W2,
    const float* __restrict__ W3, const float* __restrict__ W4,
    const float* __restrict__ W0, const float* __restrict__ b0,
    _Float16* __restrict__ out)
{
    int t = blockIdx.x * blockDim.x + threadIdx.x;
    if (t >= 6912) return;
    int lane = t & 63;
    int frag = t >> 6;                 // 0..107
    int col  = lane & 15;
    int kq   = (lane >> 4) << 2;

    if (frag < 96) {
        int l = frag >> 5, f = frag & 31;
        const float* W = (l == 0) ? W1 : (l == 1) ? W2 : W3;
        int mt = f >> 2, ks = f & 3;
        _Float16* dst = out + l * 16384 + f * 512 + lane * 8;
        int m = mt * 16 + col;
        int kbase = ks * 32 + kq;
#pragma unroll
        for (int j = 0; j < 8; ++j) {
            int k = kbase + 16 * (j >> 2) + (j & 3);
            dst[j] = (_Float16)W[k * 128 + m];
        }
    } else if (frag < 100) {
        int ks = frag - 96;
        _Float16* dst = out + 49152 + ks * 512 + lane * 8;
        int m = col;
        int kbase = ks * 32 + kq;
#pragma unroll
        for (int j = 0; j < 8; ++j) {
            int k = kbase + 16 * (j >> 2) + (j & 3);
            float v = (m < 14) ? W4[k * 14 + m] : 0.0f;
            dst[j] = (_Float16)v;
        }
    } else {
        int mt = frag - 100;
        _Float16* dst = out + 53248 + mt * 512 + lane * 8;
        int m = mt * 16 + col;
#pragma unroll
        for (int j = 0; j < 8; ++j) {
            int k = 16 * (j >> 2) + kq + (j & 3);
            float v = (k == 0) ? W0[m] : (k == 1) ? b0[m] : 0.0f;
            dst[j] = (_Float16)v;
        }
    }
}

static __device__ __forceinline__ half2v relu_cvt2(float a, float b) {
    fp16x2 h = __builtin_amdgcn_cvt_pkrtz(a, b);
    fp16x2 zz = {(__fp16)0.0f, (__fp16)0.0f};
    h = __builtin_elementwise_max(h, zz);
    return __builtin_bit_cast(half2v, h);
}

// One hidden 128->128 layer, mt-outer: per mt-pair keep only acc[4][2],
// epilogue the pair straight into bout[g][mtp]. Each weight frag feeds 4 MFMAs.
static __device__ __forceinline__ void hidden_layer(
    const half8 (&bin)[4][4], half8 (&bout)[4][4],
    const float* __restrict__ bias, const _Float16* __restrict__ Al,
    int lane, int quad)
{
#pragma unroll
    for (int mtp = 0; mtp < 4; ++mtp) {
        f32x4 acc[4][2];
        half8 a[2][4];
#pragma unroll
        for (int h = 0; h < 2; ++h) {
            int mt = 2 * mtp + h;
            f32x4 bv = *(const f32x4*)(bias + mt * 16 + quad * 4);
#pragma unroll
            for (int g = 0; g < 4; ++g) acc[g][h] = bv;
#pragma unroll
            for (int ks = 0; ks < 4; ++ks)
                a[h][ks] = *(const half8*)(Al + (mt * 4 + ks) * 512 + lane * 8);
        }
        __builtin_amdgcn_s_setprio(1);
#pragma unroll
        for (int h = 0; h < 2; ++h)
#pragma unroll
            for (int ks = 0; ks < 4; ++ks)
#pragma unroll
                for (int g = 0; g < 4; ++g)
                    acc[g][h] = __builtin_amdgcn_mfma_f32_16x16x32_f16(a[h][ks], bin[g][ks], acc[g][h], 0, 0, 0);
        __builtin_amdgcn_s_setprio(0);
#pragma unroll
        for (int g = 0; g < 4; ++g) {
            half2v p0 = relu_cvt2(acc[g][0][0], acc[g][0][1]);
            half2v p1 = relu_cvt2(acc[g][0][2], acc[g][0][3]);
            half2v p2 = relu_cvt2(acc[g][1][0], acc[g][1][1]);
            half2v p3 = relu_cvt2(acc[g][1][2], acc[g][1][3]);
            bout[g][mtp][0] = p0[0]; bout[g][mtp][1] = p0[1];
            bout[g][mtp][2] = p1[0]; bout[g][mtp][3] = p1[1];
            bout[g][mtp][4] = p2[0]; bout[g][mtp][5] = p2[1];
            bout[g][mtp][6] = p3[0]; bout[g][mtp][7] = p3[1];
        }
    }
}

__global__ __launch_bounds__(256, 2) void nflow_kernel(
    const float* __restrict__ x, const float* __restrict__ z,
    const float* __restrict__ b1, const float* __restrict__ b2,
    const float* __restrict__ b3, const float* __restrict__ b4v,
    const _Float16* __restrict__ Af, float* __restrict__ y, int N)
{
    __shared__ float phis[256][20];   // 20480 B; stride 20 f32 keeps b128 aligned

    const int tid  = threadIdx.x;
    const int lane = tid & 63;
    const int wid  = tid >> 6;
    const int col  = lane & 15;
    const int quad = lane >> 4;
    const int sbase = blockIdx.x * 256 + wid * 64;   // wave's 64 samples (4 groups of 16)

    half8 bufA[4][4], bufB[4][4];

    // ---- layer 0 as MFMA: h0 = relu([x,1]·[W0;b0]) -> bufA
    {
        half8 bx[4];
#pragma unroll
        for (int g = 0; g < 4; ++g) {
            int s = sbase + g * 16 + col;
            float xv = (s < N) ? x[s] : 0.0f;
            half8 t = {};
            if (quad == 0) { t[0] = (_Float16)xv; t[1] = (_Float16)1.0f; }
            bx[g] = t;
        }
#pragma unroll
        for (int mtp = 0; mtp < 4; ++mtp) {
            f32x4 acc[4][2];
            half8 a[2];
#pragma unroll
            for (int h = 0; h < 2; ++h)
                a[h] = *(const half8*)(Af + 53248 + (2 * mtp + h) * 512 + lane * 8);
            __builtin_amdgcn_s_setprio(1);
#pragma unroll
            for (int h = 0; h < 2; ++h)
#pragma unroll
                for (int g = 0; g < 4; ++g)
                    acc[g][h] = __builtin_amdgcn_mfma_f32_16x16x32_f16(a[h], bx[g], (f32x4){0.f,0.f,0.f,0.f}, 0, 0, 0);
            __builtin_amdgcn_s_setprio(0);
#pragma unroll
            for (int g = 0; g < 4; ++g) {
                half2v p0 = relu_cvt2(acc[g][0][0], acc[g][0][1]);
                half2v p1 = relu_cvt2(acc[g][0][2], acc[g][0][3]);
                half2v p2 = relu_cvt2(acc[g][1][0], acc[g][1][1]);
                half2v p3 = relu_cvt2(acc[g][1][2], acc[g][1][3]);
                bufA[g][mtp][0] = p0[0]; bufA[g][mtp][1] = p0[1];
                bufA[g][mtp][2] = p1[0]; bufA[g][mtp][3] = p1[1];
                bufA[g][mtp][4] = p2[0]; bufA[g][mtp][5] = p2[1];
                bufA[g][mtp][6] = p3[0]; bufA[g][mtp][7] = p3[1];
            }
        }
    }

    // ---- hidden layers 1..3 (alternating buffers)
    hidden_layer(bufA, bufB, b1, Af,         lane, quad);
    hidden_layer(bufB, bufA, b2, Af + 16384, lane, quad);
    hidden_layer(bufA, bufB, b3, Af + 32768, lane, quad);

    // ---- layer 4: phi = W4^T·h + b4 (bias in acc init)
    {
        f32x4 acc4[4];
        f32x4 binit;
#pragma unroll
        for (int r = 0; r < 4; ++r) {
            int comp = quad * 4 + r;
            binit[r] = (comp < 14) ? b4v[comp] : 0.0f;
        }
#pragma unroll
        for (int g = 0; g < 4; ++g) acc4[g] = binit;
        __builtin_amdgcn_s_setprio(1);
#pragma unroll
        for (int ks = 0; ks < 4; ++ks) {
            half8 a = *(const half8*)(Af + 49152 + ks * 512 + lane * 8);
#pragma unroll
            for (int g = 0; g < 4; ++g)
                acc4[g] = __builtin_amdgcn_mfma_f32_16x16x32_f16(a, bufB[g][ks], acc4[g], 0, 0, 0);
        }
        __builtin_amdgcn_s_setprio(0);
#pragma unroll
        for (int g = 0; g < 4; ++g)
            *(f32x4*)&phis[wid * 64 + g * 16 + col][quad * 4] = acc4[g];
    }

    __syncthreads();

    // ---- RQS inverse: all 256 threads, one sample each
    {
        int gs = blockIdx.x * 256 + tid;
        if (gs < N) {
            float ph[16];
            *(f32x4*)&ph[0]  = *(const f32x4*)&phis[tid][0];
            *(f32x4*)&ph[4]  = *(const f32x4*)&phis[tid][4];
            *(f32x4*)&ph[8]  = *(const f32x4*)&phis[tid][8];
            *(f32x4*)&ph[12] = *(const f32x4*)&phis[tid][12];

            float mw = ph[0], mh = ph[5];
#pragma unroll
            for (int i = 1; i < 5; ++i) { mw = fmaxf(mw, ph[i]); mh = fmaxf(mh, ph[5 + i]); }
            float ew[5], eh[5];
            float sw = 0.f, sh = 0.f;
#pragma unroll
            for (int i = 0; i < 5; ++i) {
                ew[i] = __expf(ph[i] - mw);      sw += ew[i];
                eh[i] = __expf(ph[5 + i] - mh);  sh += eh[i];
            }
            float iw = 10.0f / sw, ih = 10.0f / sh;
            float xk[6], yk[6], dk[6];
            xk[0] = -5.0f; yk[0] = -5.0f;
#pragma unroll
            for (int i = 0; i < 5; ++i) {
                xk[i + 1] = xk[i] + ew[i] * iw;
                yk[i + 1] = yk[i] + eh[i] * ih;
            }
            dk[0] = 1.0f; dk[5] = 1.0f;
#pragma unroll
            for (int i = 0; i < 4; ++i) {
                float v = ph[10 + i];
                dk[i + 1] = 0.0001f + fmaxf(v, 0.0f) + __logf(1.0f + __expf(-fabsf(v)));
            }
            float zv = z[gs];
            float zc = fminf(fmaxf(zv, -5.0f), 5.0f);
            int k = 0;
#pragma unroll
            for (int i = 1; i <= 4; ++i) k += (zc >= yk[i]) ? 1 : 0;
            float x0 = xk[0], x1 = xk[1], y0 = yk[0], y1 = yk[1], d0 = dk[0], d1 = dk[1];
#pragma unroll
            for (int i = 1; i < 5; ++i)
                if (k == i) { x0 = xk[i]; x1 = xk[i + 1]; y0 = yk[i]; y1 = yk[i + 1]; d0 = dk[i]; d1 = dk[i + 1]; }
            float dx = x1 - x0, dy = y1 - y0;
            float s  = dy / dx;
            float tt = zc - y0;
            float mm = d0 + d1 - 2.0f * s;
            float aa = dy * (s - d0) + tt * mm;
            float bb2 = dy * d0 - tt * mm;
            float cc = -s * tt;
            float disc = fmaxf(bb2 * bb2 - 4.0f * aa * cc, 0.0f);
            float xi   = (2.0f * cc) / (-bb2 - sqrtf(disc));
            float xin  = x0 + xi * dx;
            y[gs] = (fabsf(zv) >= 5.0f) ? zv : xin;
        }
    }
}

extern "C" void kernel_launch(void* const* d_in, const int* in_sizes, int n_in,
                              void* d_out, int out_size, void* d_ws, size_t ws_size,
                              hipStream_t stream) {
    const float* x  = (const float*)d_in[0];
    const float* z  = (const float*)d_in[1];
    const float* W0 = (const float*)d_in[2];
    const float* b0 = (const float*)d_in[3];
    const float* W1 = (const float*)d_in[4];
    const float* b1 = (const float*)d_in[5];
    const float* W2 = (const float*)d_in[6];
    const float* b2 = (const float*)d_in[7];
    const float* W3 = (const float*)d_in[8];
    const float* b3 = (const float*)d_in[9];
    const float* W4 = (const float*)d_in[10];
    const float* b4 = (const float*)d_in[11];
    float* y = (float*)d_out;
    int N = in_sizes[0];

    _Float16* wsH = (_Float16*)d_ws;
    prep_kernel<<<27, 256, 0, stream>>>(W1, W2, W3, W4, W0, b0, wsH);
    int nblk = (N + 255) / 256;
    nflow_kernel<<<nblk, 256, 0, stream>>>(x, z, b1, b2, b3, b4, wsH, y, N);
}